// Round 9
// baseline (151.303 us; speedup 1.0000x reference)
//
#include <hip/hip_runtime.h>
#include <hip/hip_bf16.h>
#include <hip/hip_cooperative_groups.h>

namespace cg = cooperative_groups;

// loss = (100/N^2) * [3*s_tt + s_rr + s_dd + s_ii - 2*(s_tr + s_td + s_ti)]
// where s_ab = || n_a^T n_b ||_F^2   (n_x = row-normalized input, N=4096, D=512)
//
// SINGLE cooperative dispatch (dispatch-count is the measured bottleneck:
// ~4 us launch overhead per dispatch; kernels themselves are near their
// floors). 256 blocks x 512 threads, exactly 1 block/CU (131 KB LDS).
//
// Phase 1 (= proven K1): SINGLE-READ fused rownorm + scale(16/||r||) + fp8
//   cast + transpose -> nT8[ ((mod*64+kb)*512 + c)*64 + dk ] (8 MB,
//   k-blocked); zeroes d_out. Block bx: strip bx&63, mod bx>>6.
// grid.sync() (device-scope fence: nT8 visible across XCDs)
// Phase 2 (= proven R5 K2 structure, best measured): TN-GEMMs 512x512 fp8
//   via MX-scaled mfma_scale_f32_16x16x128_f8f6f4, unit scales (0x7F) =
//   plain fp8 product. 336 jobs packed 2-per-block: sub-block s (128 thr,
//   2 waves) runs job bx+256*s. Per job: wave0 stages A, wave1 stages B
//   (8 global_load_lds/chunk), 4-buffer LDS (64 KB/job), 3-deep prefetch,
//   per-wave counted vmcnt(16/16/8/0) + raw s_barrier (no drain), opaque
//   asm ds_read_b128 + lgkmcnt(0) + sched_barrier before MFMA. Idle subs
//   run a matched 32-barrier loop. Pair-grouped bijective XCD swizzle
//   (slot&7)*42 + slot>>3 keeps a group's panels L2-resident; both subs of
//   a block land in the same group. Local Frobenius -> 1 atomic/job.
//
// INVARIANT: Frobenius is local only over the OUTPUT (M x N) partition;
// every job integrates the FULL K=4096. K is never split.
// Frobenius structure => immune to any consistent K/row/col permutation and
// to MFMA operand/C/D layouts (A and B always loaded with identical
// formulas); x16 pre-scale folded into normalization, /16^4 at the end.

typedef __attribute__((ext_vector_type(4))) float floatx4;
typedef __attribute__((ext_vector_type(2))) long long llx2;
typedef __attribute__((ext_vector_type(8))) int intx8;

typedef __attribute__((address_space(3))) unsigned char* lds_u8p;
typedef const __attribute__((address_space(3))) unsigned char* lds_cu8p;

#define N_ROWS 4096
#define DDIM   512
// 100 / (4096^2 * 16^4)
#define LOSS_SCALE 9.094947017729282e-11f

__device__ __forceinline__ const float* sel_mod(int mod, const float* a,
                                                const float* b, const float* c,
                                                const float* d) {
  return mod == 0 ? a : mod == 1 ? b : mod == 2 ? c : d;
}

// bf16 RNE round-trip (keeps nT8 numerics identical to the bf16 pipeline)
__device__ __forceinline__ float bfr(float x) {
  __hip_bfloat16 h = __float2bfloat16(x);
  unsigned short u = *(unsigned short*)&h;
  return __uint_as_float(((unsigned int)u) << 16);
}

// Opaque LDS read: compiler's waitcnt pass sees a register-only asm and
// inserts no vmcnt/lgkmcnt around it; WE wait with lgkmcnt(0) before use.
__device__ __forceinline__ llx2 ldsr16(lds_cu8p p) {
  llx2 r;
  asm volatile("ds_read_b128 %0, %1" : "=v"(r) : "v"(p));
  return r;
}

__device__ __forceinline__ void stage_half(
    const unsigned char* __restrict__ mbase, int cbase, int k0,
    lds_u8p dst, int lane) {
  // One wave stages one 64-col x K=128 panel chunk (8 global_load_lds).
  // k-blocked layout: 16B k-slot gc of col c sits at
  //   ((kb0 + (gc>>2))*512 + c)*64 + (gc&3)*16   (== k-offset gc*16).
  // 16B-chunk XOR swizzle on the GLOBAL side: LDS slot s of local row r
  // holds global k-slot s ^ ((r>>1)&7); LDS side is the wave-uniform base +
  // lane*16 required by global_load_lds.
  int rr = lane >> 3;  // row 0..7 within the 8-row staging group
  int s = lane & 7;    // 16B slot within the 128B k-run
  int kb0 = k0 >> 6;
#pragma unroll
  for (int c = 0; c < 8; ++c) {
    int row = c * 8 + rr;
    int gc = s ^ ((row >> 1) & 7);
    const unsigned char* g =
        mbase + ((size_t)(kb0 + (gc >> 2)) * 512 + cbase + row) * 64 +
        (gc & 3) * 16;
    __builtin_amdgcn_global_load_lds(
        (__attribute__((address_space(1))) void*)(void*)g,
        (__attribute__((address_space(3))) void*)(dst + c * 1024),
        16, 0, 0);
  }
}

__device__ __forceinline__ void compute_w(lds_cu8p lsb, floatx4 acc[4][2],
                                          int wn, int lm, int lq) {
  // Lane (lm,lq): A rows mi*16+lm, B rows wn+ni*16+lm; 32 B of K per lane
  // (two asm ds_read_b128 at unswizzled slots lq*2, lq*2+1) feed ONE K=128
  // mfma_scale per (mi,ni). Unit scales (E8M0 0x7F) => plain fp8 product.
  // Any operand-layout mismatch is a uniform row/col/K permutation applied
  // identically to A and B => Frobenius-invariant.
  intx8 A8[4], B8[2];
#pragma unroll
  for (int mi = 0; mi < 4; ++mi) {
    int row = mi * 16 + lm;  // local A row 0..63
    int sw = (row >> 1) & 7;
    *(llx2*)&A8[mi] = ldsr16(lsb + row * 128 + ((lq * 2) ^ sw) * 16);
    *((llx2*)&A8[mi] + 1) =
        ldsr16(lsb + row * 128 + ((lq * 2 + 1) ^ sw) * 16);
  }
#pragma unroll
  for (int ni = 0; ni < 2; ++ni) {
    int row = wn + ni * 16 + lm;  // local B row 0..63
    int sw = (row >> 1) & 7;
    *(llx2*)&B8[ni] =
        ldsr16(lsb + 8192 + row * 128 + ((lq * 2) ^ sw) * 16);
    *((llx2*)&B8[ni] + 1) =
        ldsr16(lsb + 8192 + row * 128 + ((lq * 2 + 1) ^ sw) * 16);
  }
  // ds_read results are NOT scoreboarded: wait, then fence the scheduler so
  // the MFMAs cannot be hoisted above the wait (rule #18).
  asm volatile("s_waitcnt lgkmcnt(0)");
  __builtin_amdgcn_sched_barrier(0);
  __builtin_amdgcn_s_setprio(1);
#pragma unroll
  for (int mi = 0; mi < 4; ++mi)
#pragma unroll
    for (int ni = 0; ni < 2; ++ni)
      acc[mi][ni] = __builtin_amdgcn_mfma_scale_f32_16x16x128_f8f6f4(
          A8[mi], B8[ni], acc[mi][ni], 0, 0,  // cbsz=0 (fp8), blgp=0 (fp8)
          0, 0x7F, 0, 0x7F);                  // opselA, scaleA, opselB, scaleB
  __builtin_amdgcn_s_setprio(0);
}

__global__ __launch_bounds__(512) void fused_kernel(
    const float* __restrict__ in0, const float* __restrict__ in1,
    const float* __restrict__ in2, const float* __restrict__ in3,
    unsigned char* __restrict__ nT8, float* __restrict__ out) {
  __shared__ __align__(16) unsigned char smem[131072];  // phase-1/2 union
  __shared__ float red[8];

  int bx = blockIdx.x;
  int t = threadIdx.x;

  // ======================= phase 1: preprocess =======================
  {
    int mod = bx >> 6;
    int k0 = (bx & 63) * 64;
    const float* X = sel_mod(mod, in0, in1, in2, in3) + (size_t)k0 * DDIM;

    if (bx == 0 && t == 0) out[0] = 0.f;  // accumulated by phase 2 atomics

    float* rsc = (float*)smem;                          // 256 B
    unsigned int* t8 = (unsigned int*)(smem + 256);     // 512*17*4 = 34816 B

    int a = t >> 5;   // row-group 0..15 -> rows 4a..4a+3
    int bg = t & 31;  // col-group: float4 bg within each 128-col panel

    // single global read: 4 rows x 4 panels of float4 -> 64 VGPRs
    float4 v[4][4];  // [q][p]
#pragma unroll
    for (int q = 0; q < 4; ++q)
#pragma unroll
      for (int p = 0; p < 4; ++p)
        v[q][p] =
            ((const float4*)(X + (size_t)(4 * a + q) * DDIM + p * 128))[bg];

    // row-norm partials; rows of group a live in one 32-lane half-wave
    float ss[4];
#pragma unroll
    for (int q = 0; q < 4; ++q) {
      float acc = 0.f;
#pragma unroll
      for (int p = 0; p < 4; ++p) {
        float4 u = v[q][p];
        acc += u.x * u.x + u.y * u.y + u.z * u.z + u.w * u.w;
      }
      ss[q] = acc;
    }
#pragma unroll
    for (int off = 16; off > 0; off >>= 1)
#pragma unroll
      for (int q = 0; q < 4; ++q) ss[q] += __shfl_down(ss[q], off, 32);
    if (bg == 0) {
#pragma unroll
      for (int q = 0; q < 4; ++q)
        rsc[4 * a + q] = 16.0f / fmaxf(sqrtf(ss[q]), 1e-12f);  // x16 folded
    }
    __syncthreads();

    float sc[4];
#pragma unroll
    for (int q = 0; q < 4; ++q) sc[q] = rsc[4 * a + q];

    // scale -> bf16 round -> fp8 pack (4 k-rows per word), from registers
#pragma unroll
    for (int p = 0; p < 4; ++p)
#pragma unroll
      for (int j = 0; j < 4; ++j) {
        float f0 = bfr(((const float*)&v[0][p])[j] * sc[0]);
        float f1 = bfr(((const float*)&v[1][p])[j] * sc[1]);
        float f2 = bfr(((const float*)&v[2][p])[j] * sc[2]);
        float f3 = bfr(((const float*)&v[3][p])[j] * sc[3]);
        unsigned int pk = __builtin_amdgcn_cvt_pk_fp8_f32(f0, f1, 0, 0);
        pk = __builtin_amdgcn_cvt_pk_fp8_f32(f2, f3, pk, 1);  // k-order bytes
        t8[(p * 128 + bg * 4 + j) * 17 + a] = pk;
      }
    __syncthreads();

    // one contiguous 32 KB store per block (k-blocked layout)
    size_t rbase = (size_t)(mod * 64 + (bx & 63)) * 32768;
#pragma unroll
    for (int it = 0; it < 4; ++it) {
      int idx = it * 512 + t;
      int col = idx >> 2;
      int g = idx & 3;
      uint4 o;
      o.x = t8[col * 17 + g * 4 + 0];
      o.y = t8[col * 17 + g * 4 + 1];
      o.z = t8[col * 17 + g * 4 + 2];
      o.w = t8[col * 17 + g * 4 + 3];
      *(uint4*)(nT8 + rbase + (size_t)idx * 16) = o;
    }
  }

  // =============== grid-wide sync (device-scope fence) ===============
  cg::this_grid().sync();

  // ========================= phase 2: gram ===========================
  int sub = t >> 7;   // 0..3 (subs 2,3 always idle)
  int tl = t & 127;
  int slot = bx + 256 * sub;
  bool active = (sub < 2) && (slot < 336);

  float wgt = 0.f;
  int w = tl >> 6;     // wave within sub: 0 stages A, 1 stages B
  int lane = tl & 63;
  int lm = lane & 15;
  int lq = lane >> 4;
  int wn = w * 32;

  if (active) {
    // bijective XCD-group swizzle: 336 = 8 x 42; both subs of a block share
    // (slot&7) => same pair-group neighborhood on this XCD.
    int job = (slot & 7) * 42 + (slot >> 3);

    // decode job -> (ti, tj, idx-within-group); group-major over unordered
    // strip pairs {ti,tj}: diag groups 7 jobs, off-diag groups 10 jobs.
    int rem = job, ti = 7, tj = 7;
    for (int i = 0; i < 8; ++i) {
      int rowlen = 7 + 10 * (7 - i);
      if (rem < rowlen) {
        if (rem < 7) {
          ti = i; tj = i;
        } else {
          int r2 = rem - 7;
          ti = i; tj = i + 1 + r2 / 10;
          rem = r2 % 10;
        }
        break;
      }
      rem -= rowlen;
    }

    int pa_, pb_, a0, b0;
    if (ti == tj) {
      if (rem < 4) { pa_ = pb_ = rem; wgt = (rem == 3) ? 3.f : 1.f; }
      else         { pa_ = 3; pb_ = rem - 4; wgt = -2.f; }
      a0 = ti * 64; b0 = ti * 64;
    } else {
      if (rem < 4) {
        pa_ = pb_ = rem; wgt = (rem == 3) ? 6.f : 2.f;  // off-diag self x2
        a0 = ti * 64; b0 = tj * 64;
      } else {
        int k = rem - 4;
        pa_ = 3; pb_ = k >> 1; wgt = -2.f;
        if (k & 1) { a0 = tj * 64; b0 = ti * 64; }
        else       { a0 = ti * 64; b0 = tj * 64; }
      }
    }

    const unsigned char* Abase = nT8 + (size_t)pa_ * 2097152;
    const unsigned char* Bbase = nT8 + (size_t)pb_ * 2097152;
    const unsigned char* mbase = (w == 0) ? Abase : Bbase;
    int cb = (w == 0) ? a0 : b0;
    int soff = w * 8192;
    lds_u8p sb = (lds_u8p)(void*)&smem[0] + sub * 65536;  // 4 bufs x 16 KB

    floatx4 zero = {0.f, 0.f, 0.f, 0.f};
    floatx4 acc[4][2];
#pragma unroll
    for (int mi = 0; mi < 4; ++mi)
#pragma unroll
      for (int ni = 0; ni < 2; ++ni) acc[mi][ni] = zero;

    // 32 chunks of K=128, 4 buffers, 3-deep prefetch. Per-wave counted
    // vmcnt (8 own loads per stage, 3 chunks in flight = 24): wait own<=16
    // => own chunk-i loads landed; raw s_barrier (no drain) publishes both
    // halves. 32 barriers total (matched by idle subs).
    stage_half(mbase, cb, 0, sb + 0 * 16384 + soff, lane);
    stage_half(mbase, cb, 128, sb + 1 * 16384 + soff, lane);
    stage_half(mbase, cb, 256, sb + 2 * 16384 + soff, lane);
    for (int i = 0; i < 29; ++i) {
      asm volatile("s_waitcnt vmcnt(16)");
      __builtin_amdgcn_sched_barrier(0);
      __builtin_amdgcn_s_barrier();
      stage_half(mbase, cb, (i + 3) * 128,
                 sb + ((i + 3) & 3) * 16384 + soff, lane);
      compute_w((lds_cu8p)(sb + (i & 3) * 16384), acc, wn, lm, lq);
    }
    asm volatile("s_waitcnt vmcnt(16)");
    __builtin_amdgcn_sched_barrier(0);
    __builtin_amdgcn_s_barrier();
    compute_w((lds_cu8p)(sb + 1 * 16384), acc, wn, lm, lq);  // chunk 29
    asm volatile("s_waitcnt vmcnt(8)");
    __builtin_amdgcn_sched_barrier(0);
    __builtin_amdgcn_s_barrier();
    compute_w((lds_cu8p)(sb + 2 * 16384), acc, wn, lm, lq);  // chunk 30
    asm volatile("s_waitcnt vmcnt(0)");
    __builtin_amdgcn_sched_barrier(0);
    __builtin_amdgcn_s_barrier();
    compute_w((lds_cu8p)(sb + 3 * 16384), acc, wn, lm, lq);  // chunk 31

    // Local Frobenius: C/D layout is a bijection -> sum of squares exact.
    float s = 0.f;
#pragma unroll
    for (int mi = 0; mi < 4; ++mi)
#pragma unroll
      for (int ni = 0; ni < 2; ++ni)
#pragma unroll
        for (int r = 0; r < 4; ++r) {
          float v = acc[mi][ni][r];
          s += v * v;
        }
#pragma unroll
    for (int off = 32; off > 0; off >>= 1) s += __shfl_down(s, off, 64);
    if (lane == 0) red[(sub << 1) | w] = s;
  } else {
    // matched barrier count: pipeline above hits s_barrier exactly 32 times
    for (int i = 0; i < 32; ++i) __builtin_amdgcn_s_barrier();
  }
  __syncthreads();
  if (active && tl == 0)
    atomicAdd(out, wgt * LOSS_SCALE * (red[sub * 2] + red[sub * 2 + 1]));
}

extern "C" void kernel_launch(void* const* d_in, const int* in_sizes, int n_in,
                              void* d_out, int out_size, void* d_ws, size_t ws_size,
                              hipStream_t stream) {
  const float* in_rgb   = (const float*)d_in[0];
  const float* in_depth = (const float*)d_in[1];
  const float* in_ir    = (const float*)d_in[2];
  const float* in_t     = (const float*)d_in[3];
  unsigned char* nT8 = (unsigned char*)d_ws;  // 8 MB fp8, k-blocked layout
  float* outp = (float*)d_out;

  void* args[6];
  args[0] = (void*)&in_rgb;
  args[1] = (void*)&in_depth;
  args[2] = (void*)&in_ir;
  args[3] = (void*)&in_t;
  args[4] = (void*)&nT8;
  args[5] = (void*)&outp;
  hipLaunchCooperativeKernel((const void*)fused_kernel, dim3(256), dim3(512),
                             args, 0, stream);
}

// Round 10
// 96.321 us; speedup vs baseline: 1.5708x; 1.5708x over previous
//
#include <hip/hip_runtime.h>
#include <hip/hip_bf16.h>

// loss = (100/N^2) * [3*s_tt + s_rr + s_dd + s_ii - 2*(s_tr + s_td + s_ti)]
// where s_ab = || n_a^T n_b ||_F^2   (n_x = row-normalized input, N=4096, D=512)
//
// fp8 pipeline, 2 dispatches. nT8 layout is k-blocked:
//   nT8[ ((mod*64 + kb)*512 + c)*64 + dk ],  kb = k/64, dk = k%64  (8 MB)
//
// INVARIANT: the Frobenius reduction is local only over the OUTPUT (M x N)
// partition across BLOCKS; K is split across WAVES of one block ONLY, with
// the partial grams summed elementwise (via LDS) BEFORE squaring.
//
// K1 preprocess (proven, unchanged): SINGLE-READ fused rownorm +
//   scale(16/||r||) + fp8 cast + transpose; zeroes d_out. 64-row strips,
//   256 blocks (1/CU), 512 threads, register-resident 4x4 blocks.
// K2 gram (new: BARRIER-FREE, cadence-free): R9's counters showed the
//   staged pipeline ~97% idle (MfmaUtil 3%) -- the per-chunk
//   wait/s_barrier/LDS-DMA cadence dominated. Now: 336 blocks x 4 waves;
//   wave w integrates K in [1024w, 1024w+1024) (8 chunks of 128) over the
//   FULL 64x64 tile (4x4 frags, 16 MFMA/chunk via MX-scaled
//   mfma_scale_f32_16x16x128_f8f6f4, unit scales 0x7F = plain fp8 product).
//   Fragments load directly from L2/L3 to registers (contiguous 1 KB
//   segments; plain loads -> compiler's counted vmcnt), 2-deep register
//   double-buffer, zero LDS / zero barriers in the main loop. Epilogue:
//   4 partial accs summed through a 64 KB LDS buffer (conflict-free b32
//   layout), squared once, block-reduce -> 1 atomic/block. Pair-grouped
//   bijective XCD swizzle keeps a group's panels L2-resident. SELF products
//   symmetric => tiles i<=j only, off-diag x2: 4*36 + 3*64 = 336 jobs.
// Frobenius structure => immune to any consistent K/row/col permutation and
// to MFMA operand/C/D layouts (A and B always loaded with identical
// formulas); x16 pre-scale folded into normalization, /16^4 at the end.

typedef __attribute__((ext_vector_type(4))) float floatx4;
typedef __attribute__((ext_vector_type(2))) long long llx2;
typedef __attribute__((ext_vector_type(8))) int intx8;

#define N_ROWS 4096
#define DDIM   512
// 100 / (4096^2 * 16^4)
#define LOSS_SCALE 9.094947017729282e-11f

__device__ __forceinline__ const float* sel_mod(int mod, const float* a,
                                                const float* b, const float* c,
                                                const float* d) {
  return mod == 0 ? a : mod == 1 ? b : mod == 2 ? c : d;
}

// bf16 RNE round-trip (keeps nT8 numerics identical to the bf16 pipeline)
__device__ __forceinline__ float bfr(float x) {
  __hip_bfloat16 h = __float2bfloat16(x);
  unsigned short u = *(unsigned short*)&h;
  return __uint_as_float(((unsigned int)u) << 16);
}

__global__ __launch_bounds__(512) void preprocess_kernel(
    const float* __restrict__ in0, const float* __restrict__ in1,
    const float* __restrict__ in2, const float* __restrict__ in3,
    unsigned char* __restrict__ nT8, float* __restrict__ out) {
  // grid: x = 64 (k-strips of 64 rows = one kb block), y = 4 (mod).
  int mod = blockIdx.y;
  int k0 = blockIdx.x * 64;
  const float* X = sel_mod(mod, in0, in1, in2, in3) + (size_t)k0 * DDIM;

  if (blockIdx.x == 0 && blockIdx.y == 0 && threadIdx.x == 0)
    out[0] = 0.f;  // d_out re-poisoned each call; gram (next dispatch) accums

  __shared__ float rsc[64];
  // fp8-packed transpose tile: [512 cols][16 row-groups + 1 pad] words.
  // stride 17 (odd): pack-writes ~8 banks, out-phase b32 reads ~2-way (free).
  __shared__ unsigned int t8[512 * 17];  // 34.8 KB

  int t = threadIdx.x;
  int a = t >> 5;   // row-group 0..15 -> rows 4a..4a+3
  int bg = t & 31;  // col-group: float4 bg within each 128-col panel

  // single global read: 4 rows x 4 panels of float4 -> 64 VGPRs
  float4 v[4][4];  // [q][p]
#pragma unroll
  for (int q = 0; q < 4; ++q)
#pragma unroll
    for (int p = 0; p < 4; ++p)
      v[q][p] = ((const float4*)(X + (size_t)(4 * a + q) * DDIM + p * 128))[bg];

  // row-norm partials from registers; rows of group a live in one 32-lane
  // half-wave (t = a*32 + bg) -> width-32 shfl reduce
  float ss[4];
#pragma unroll
  for (int q = 0; q < 4; ++q) {
    float acc = 0.f;
#pragma unroll
    for (int p = 0; p < 4; ++p) {
      float4 u = v[q][p];
      acc += u.x * u.x + u.y * u.y + u.z * u.z + u.w * u.w;
    }
    ss[q] = acc;
  }
#pragma unroll
  for (int off = 16; off > 0; off >>= 1)
#pragma unroll
    for (int q = 0; q < 4; ++q) ss[q] += __shfl_down(ss[q], off, 32);
  if (bg == 0) {
#pragma unroll
    for (int q = 0; q < 4; ++q)
      rsc[4 * a + q] = 16.0f / fmaxf(sqrtf(ss[q]), 1e-12f);  // x16 folded
  }
  __syncthreads();

  float sc[4];
#pragma unroll
  for (int q = 0; q < 4; ++q) sc[q] = rsc[4 * a + q];

  // scale -> bf16 round -> fp8 pack (4 k-rows per word), straight from regs
#pragma unroll
  for (int p = 0; p < 4; ++p)
#pragma unroll
    for (int j = 0; j < 4; ++j) {
      float f0 = bfr(((const float*)&v[0][p])[j] * sc[0]);
      float f1 = bfr(((const float*)&v[1][p])[j] * sc[1]);
      float f2 = bfr(((const float*)&v[2][p])[j] * sc[2]);
      float f3 = bfr(((const float*)&v[3][p])[j] * sc[3]);
      unsigned int pk = __builtin_amdgcn_cvt_pk_fp8_f32(f0, f1, 0, 0);
      pk = __builtin_amdgcn_cvt_pk_fp8_f32(f2, f3, pk, 1);  // k-order bytes
      t8[(p * 128 + bg * 4 + j) * 17 + a] = pk;
    }
  __syncthreads();

  // output: one contiguous 32 KB region per block (k-blocked layout):
  // flat byte off = c*64 + g*16 = idx*16
  size_t rbase = (size_t)(mod * 64 + blockIdx.x) * 32768;
#pragma unroll
  for (int it = 0; it < 4; ++it) {
    int idx = it * 512 + t;
    int col = idx >> 2;  // 0..511
    int g = idx & 3;     // 16-byte k-group within the 64-row strip
    uint4 o;
    o.x = t8[col * 17 + g * 4 + 0];
    o.y = t8[col * 17 + g * 4 + 1];
    o.z = t8[col * 17 + g * 4 + 2];
    o.w = t8[col * 17 + g * 4 + 3];
    *(uint4*)(nT8 + rbase + (size_t)idx * 16) = o;
  }
}

// 32 B fragment load (two aligned 16 B loads; compiler handles vmcnt)
__device__ __forceinline__ intx8 ldfrag(const unsigned char* __restrict__ p) {
  intx8 r;
  *(llx2*)&r = *(const llx2*)p;
  *((llx2*)&r + 1) = *(const llx2*)(p + 16);
  return r;
}

__global__ __launch_bounds__(256) void gram_frob_kernel(
    const unsigned char* __restrict__ nT8, float* __restrict__ out) {
  // 336 blocks x 4 waves; wave w covers K in [1024w, 1024w+1024).
  __shared__ float pacc[4][4096];  // 64 KB: per-wave partial gram
  __shared__ float red[4];

  int bx = blockIdx.x;
  // bijective XCD-group swizzle: 336 = 8 x 42 (pair-grouped job order)
  int job = (bx & 7) * 42 + (bx >> 3);

  // decode job -> (ti, tj, idx-within-group); group-major over unordered
  // strip pairs {ti,tj}: diag groups 7 jobs, off-diag groups 10 jobs.
  int rem = job, ti = 7, tj = 7;
  for (int i = 0; i < 8; ++i) {
    int rowlen = 7 + 10 * (7 - i);
    if (rem < rowlen) {
      if (rem < 7) {
        ti = i; tj = i;
      } else {
        int r2 = rem - 7;
        ti = i; tj = i + 1 + r2 / 10;
        rem = r2 % 10;
      }
      break;
    }
    rem -= rowlen;
  }

  int pa_, pb_, a0, b0;
  float wgt;
  if (ti == tj) {
    if (rem < 4) { pa_ = pb_ = rem; wgt = (rem == 3) ? 3.f : 1.f; }
    else         { pa_ = 3; pb_ = rem - 4; wgt = -2.f; }
    a0 = ti * 64; b0 = ti * 64;
  } else {
    if (rem < 4) {
      pa_ = pb_ = rem; wgt = (rem == 3) ? 6.f : 2.f;  // off-diag self x2
      a0 = ti * 64; b0 = tj * 64;
    } else {
      int k = rem - 4;
      pa_ = 3; pb_ = k >> 1; wgt = -2.f;
      if (k & 1) { a0 = tj * 64; b0 = ti * 64; }
      else       { a0 = ti * 64; b0 = tj * 64; }
    }
  }

  int t = threadIdx.x;
  int w = t >> 6;      // wave 0..3 -> K-range [1024w, 1024w+1024)
  int lane = t & 63;
  int lm = lane & 15;  // column-within-fragment
  int lq = lane >> 4;  // 32 B k-window: kb parity (lq>>1), 32B half (lq&1)

  // fragment base, chunk 0 of wave w's K-range (R7-refcheck'd formulas):
  //   ((w*16 + (lq>>1)) * 512 + c) * 64 + (lq&1)*32,  c = cb + frag*16 + lm
  size_t lkb =
      ((size_t)(w * 16 + (lq >> 1)) * 512 + lm) * 64 + (size_t)(lq & 1) * 32;
  const unsigned char* pA =
      nT8 + (size_t)pa_ * 2097152 + lkb + (size_t)a0 * 64;
  const unsigned char* pB =
      nT8 + (size_t)pb_ * 2097152 + lkb + (size_t)b0 * 64;
#define FRAG_STRIDE 1024    // +16 cols
#define CHUNK_STRIDE 65536  // +2 kb-blocks (K advances 128)
#define ADV do { pA += CHUNK_STRIDE; pB += CHUNK_STRIDE; } while (0)

  floatx4 zero = {0.f, 0.f, 0.f, 0.f};
  floatx4 acc[4][4];
#pragma unroll
  for (int mi = 0; mi < 4; ++mi)
#pragma unroll
    for (int ni = 0; ni < 4; ++ni) acc[mi][ni] = zero;

  intx8 ae[4], be[4], ao[4], bo[4];

#define LDALL(AR, BR)                                                       \
  do {                                                                      \
    _Pragma("unroll")                                                       \
    for (int f_ = 0; f_ < 4; ++f_) {                                        \
      AR[f_] = ldfrag(pA + f_ * FRAG_STRIDE);                               \
      BR[f_] = ldfrag(pB + f_ * FRAG_STRIDE);                               \
    }                                                                       \
  } while (0)

#define MFMA16(AR, BR)                                                      \
  do {                                                                      \
    __builtin_amdgcn_s_setprio(1);                                          \
    _Pragma("unroll")                                                       \
    for (int mi_ = 0; mi_ < 4; ++mi_)                                       \
      _Pragma("unroll")                                                     \
      for (int ni_ = 0; ni_ < 4; ++ni_)                                     \
        acc[mi_][ni_] = __builtin_amdgcn_mfma_scale_f32_16x16x128_f8f6f4(   \
            AR[mi_], BR[ni_], acc[mi_][ni_], 0, 0, 0, 0x7F, 0, 0x7F);       \
    __builtin_amdgcn_s_setprio(0);                                          \
  } while (0)

  // 8 chunks of K=128, 2-deep register double-buffer, NO barriers/LDS.
  LDALL(ae, be);  // chunk 0
#pragma unroll
  for (int ch = 0; ch < 6; ch += 2) {
    ADV;
    LDALL(ao, bo);   // chunk ch+1
    MFMA16(ae, be);  // chunk ch
    ADV;
    LDALL(ae, be);   // chunk ch+2
    MFMA16(ao, bo);  // chunk ch+1
  }
  ADV;
  LDALL(ao, bo);   // chunk 7
  MFMA16(ae, be);  // chunk 6
  MFMA16(ao, bo);  // chunk 7

  // Cross-wave K-reduction BEFORE squaring: each wave stores its partial
  // gram to its own LDS region (conflict-free b32 layout: consecutive lanes
  // -> consecutive words), then all threads sum the 4 regions elementwise,
  // square, and block-reduce. C/D lane mapping is instruction-fixed and
  // identical across waves -> elementwise sum is the true full-K gram.
#pragma unroll
  for (int mi = 0; mi < 4; ++mi)
#pragma unroll
    for (int ni = 0; ni < 4; ++ni)
#pragma unroll
      for (int r = 0; r < 4; ++r)
        pacc[w][r * 1024 + (mi * 4 + ni) * 64 + lane] = acc[mi][ni][r];
  __syncthreads();

  float s = 0.f;
#pragma unroll
  for (int it = 0; it < 16; ++it) {
    int idx = it * 256 + t;
    float v = pacc[0][idx] + pacc[1][idx] + pacc[2][idx] + pacc[3][idx];
    s += v * v;
  }
#pragma unroll
  for (int off = 32; off > 0; off >>= 1) s += __shfl_down(s, off, 64);
  if (lane == 0) red[w] = s;
  __syncthreads();
  if (t == 0)
    atomicAdd(out, wgt * LOSS_SCALE * (red[0] + red[1] + red[2] + red[3]));
}

extern "C" void kernel_launch(void* const* d_in, const int* in_sizes, int n_in,
                              void* d_out, int out_size, void* d_ws, size_t ws_size,
                              hipStream_t stream) {
  const float* in_rgb   = (const float*)d_in[0];
  const float* in_depth = (const float*)d_in[1];
  const float* in_ir    = (const float*)d_in[2];
  const float* in_t     = (const float*)d_in[3];

  unsigned char* nT8 = (unsigned char*)d_ws;  // 8 MB fp8, k-blocked layout

  preprocess_kernel<<<dim3(64, 4), 512, 0, stream>>>(
      in_rgb, in_depth, in_ir, in_t, nT8, (float*)d_out);
  gram_frob_kernel<<<dim3(336), 256, 0, stream>>>(nT8, (float*)d_out);
}